// Round 10
// baseline (140.873 us; speedup 1.0000x reference)
//
#include <hip/hip_runtime.h>
#include <hip/hip_bf16.h>

// Problem constants (fixed by the reference file).
#define Bq  4
#define Cq  64
#define Hq  256
#define Wq  256
#define Nq  300000
#define Kq  16
#define NVq 6890
#define TOTAL (Bq * Nq)

#define SZ_FMTB ((size_t)Bq * Hq * Wq * Cq * 2)   // 32 MiB bf16 map

#define NXCD 8
#define NBLK_S ((TOTAL + 255) / 256)              // 4688 = 8 * 586, clean

typedef float          f32x4 __attribute__((ext_vector_type(4)));
typedef unsigned short u16x4 __attribute__((ext_vector_type(4)));

__device__ __forceinline__ float bf2f(unsigned short u) {
    return __uint_as_float(((unsigned)u) << 16);
}
__device__ __forceinline__ unsigned short f2bf(float x) {
    __hip_bfloat16 v = __float2bfloat16(x);   // RNE
    return *reinterpret_cast<unsigned short*>(&v);
}

// Shared per-n scalar pipeline: flat g -> pixel-space sample point.
struct SampleParams { float px, py; int b; };
__device__ __forceinline__ SampleParams compute_center(
    int g, const float* __restrict__ verts, const float* __restrict__ bary,
    const int* __restrict__ parents)
{
    const int b = g / Nq;
    const int n = g - b * Nq;

    const int k = n & (Kq - 1);
    const float w0 = bary[k * 3 + 0];
    const float w1 = bary[k * 3 + 1];
    const float w2 = bary[k * 3 + 2];

    const int p0 = parents[n * 3 + 0];
    const int p1 = parents[n * 3 + 1];
    const int p2 = parents[n * 3 + 2];

    const float* vb = verts + (size_t)b * NVq * 2;
    const float cx = w0 * vb[p0 * 2 + 0] + w1 * vb[p1 * 2 + 0] + w2 * vb[p2 * 2 + 0];
    const float cy = w0 * vb[p0 * 2 + 1] + w1 * vb[p1 * 2 + 1] + w2 * vb[p2 * 2 + 1];

    // replicate reference's normalize -> denormalize round-trip exactly
    const float gx = cx / (float)(Wq - 1) * 2.0f - 1.0f;
    const float gy = cy / (float)(Hq - 1) * 2.0f - 1.0f;

    SampleParams sp;
    sp.px = (gx + 1.0f) * 0.5f * (float)(Wq - 1);
    sp.py = (gy + 1.0f) * 0.5f * (float)(Hq - 1);
    sp.b  = b;
    return sp;
}

// ---------------------------------------------------------------------------
// K1: transpose + quantize (B,C,H,W) fp32 -> (B,H,W,C) bf16.
// ---------------------------------------------------------------------------
__global__ __launch_bounds__(256) void transpose_kernel(
    const float* __restrict__ fm, unsigned short* __restrict__ fmtb)
{
    __shared__ float tile[64][65];
    const int blk = blockIdx.x;                 // 0 .. B*(HW/64)-1
    const int b   = blk / (Hq * Wq / 64);
    const int hw0 = (blk % (Hq * Wq / 64)) * 64;
    const int t   = threadIdx.x;
    const int tx  = t & 63;
    const int ty  = t >> 6;

    const float* src = fm + (size_t)b * Cq * (Hq * Wq);
    #pragma unroll
    for (int c = ty; c < 64; c += 4) {
        tile[c][tx] = __builtin_nontemporal_load(
            src + (size_t)c * (Hq * Wq) + hw0 + tx);           // coalesced
    }
    __syncthreads();

    // store: 8 pixels per iter; 32 lanes/pixel, each lane packs 2 bf16 ch.
    unsigned int* dstu = (unsigned int*)(fmtb + ((size_t)b * (Hq * Wq) + hw0) * Cq);
    const int c2 = (t & 31) * 2;
    #pragma unroll
    for (int r0 = 0; r0 < 64; r0 += 8) {
        const int p = r0 + (t >> 5);
        const unsigned int lo = f2bf(tile[c2][p]);
        const unsigned int hi = f2bf(tile[c2 + 1][p]);
        dstu[p * 32 + (c2 >> 1)] = lo | (hi << 16);            // 256B/wave
    }
}

// ---------------------------------------------------------------------------
// K2: two y-half passes. Phase A per-thread params -> LDS (+active flag:
// this pass handles n iff cy0 is in its y-half). Phase B: 8 lanes/n, channel
// split {cA..cA+3, cA+32..cA+35} (line-complete NT stores). Per-XCD per-pass
// gather working set = 4 MB (one y-half of one batch slice) -> fits L2.
// XCD-chunk swizzle retained.
// ---------------------------------------------------------------------------
__global__ __launch_bounds__(256) void sample_kernel(
    const unsigned short* __restrict__ fmtb,  // (B,H,W,C) bf16
    const float* __restrict__ verts,
    const float* __restrict__ bary,
    const int*   __restrict__ parents,
    float* __restrict__ out,                  // (B,N,C) fp32
    const int   pass)                         // 0: cy0<128, 1: cy0>=128
{
    __shared__ int   s_ofs[256][4];
    __shared__ float s_wts[256][4];
    __shared__ int   s_act[256];

    const int t = threadIdx.x;

    // chunked bijective XCD swizzle (4688 = 8*586)
    const int bid   = (int)blockIdx.x;
    const int blk   = (bid % NXCD) * (NBLK_S / NXCD) + bid / NXCD;
    const int gbase = blk * 256;
    const int g     = gbase + t;

    // ---------------- Phase A ----------------
    if (g < TOTAL) {
        SampleParams sp = compute_center(g, verts, bary, parents);
        const float x0f = floorf(sp.px);
        const float y0f = floorf(sp.py);
        const float fx = sp.px - x0f;
        const float fy = sp.py - y0f;

        const int ix0 = (int)x0f, iy0 = (int)y0f;
        const int ix1 = ix0 + 1,  iy1 = iy0 + 1;

        const float vx0 = (x0f >= 0.0f        && x0f <= (float)(Wq - 1)) ? 1.0f : 0.0f;
        const float vx1 = (x0f + 1.0f >= 0.0f && x0f + 1.0f <= (float)(Wq - 1)) ? 1.0f : 0.0f;
        const float vy0 = (y0f >= 0.0f        && y0f <= (float)(Hq - 1)) ? 1.0f : 0.0f;
        const float vy1 = (y0f + 1.0f >= 0.0f && y0f + 1.0f <= (float)(Hq - 1)) ? 1.0f : 0.0f;

        const int cx0 = min(max(ix0, 0), Wq - 1);
        const int cx1 = min(max(ix1, 0), Wq - 1);
        const int cy0 = min(max(iy0, 0), Hq - 1);
        const int cy1 = min(max(iy1, 0), Hq - 1);

        s_act[t] = ((cy0 >> 7) == pass) ? 1 : 0;

        const int bb = sp.b * (Hq * Wq * Cq);
        s_ofs[t][0] = bb + (cy0 * Wq + cx0) * Cq;
        s_ofs[t][1] = bb + (cy0 * Wq + cx1) * Cq;
        s_ofs[t][2] = bb + (cy1 * Wq + cx0) * Cq;
        s_ofs[t][3] = bb + (cy1 * Wq + cx1) * Cq;

        s_wts[t][0] = (1.0f - fx) * (1.0f - fy) * vx0 * vy0;
        s_wts[t][1] = fx          * (1.0f - fy) * vx1 * vy0;
        s_wts[t][2] = (1.0f - fx) * fy          * vx0 * vy1;
        s_wts[t][3] = fx          * fy          * vx1 * vy1;
    } else {
        s_act[t] = 0;
        s_ofs[t][0] = s_ofs[t][1] = s_ofs[t][2] = s_ofs[t][3] = 0;
        s_wts[t][0] = s_wts[t][1] = s_wts[t][2] = s_wts[t][3] = 0.0f;
    }
    __syncthreads();

    // ---------------- Phase B ----------------
    const int wv   = t >> 6;
    const int lane = t & 63;
    const int q    = lane >> 3;          // 0..7 -> which n in group of 8
    const int cA   = (lane & 7) * 4;     // channels cA..cA+3 and cA+32..cA+35

    #pragma unroll 2
    for (int i = 0; i < 8; ++i) {
        const int li = wv * 64 + i * 8 + q;
        if (!s_act[li]) continue;

        const int4   o = *(const int4*)  s_ofs[li];
        const float4 w = *(const float4*)s_wts[li];

        const u16x4 a0A = *(const u16x4*)(fmtb + o.x + cA);
        const u16x4 a1A = *(const u16x4*)(fmtb + o.y + cA);
        const u16x4 a2A = *(const u16x4*)(fmtb + o.z + cA);
        const u16x4 a3A = *(const u16x4*)(fmtb + o.w + cA);
        const u16x4 a0B = *(const u16x4*)(fmtb + o.x + cA + 32);
        const u16x4 a1B = *(const u16x4*)(fmtb + o.y + cA + 32);
        const u16x4 a2B = *(const u16x4*)(fmtb + o.z + cA + 32);
        const u16x4 a3B = *(const u16x4*)(fmtb + o.w + cA + 32);

        f32x4 rA, rB;
        #pragma unroll
        for (int j = 0; j < 4; ++j) {
            rA[j] = bf2f(a0A[j]) * w.x + bf2f(a1A[j]) * w.y
                  + bf2f(a2A[j]) * w.z + bf2f(a3A[j]) * w.w;
        }
        #pragma unroll
        for (int j = 0; j < 4; ++j) {
            rB[j] = bf2f(a0B[j]) * w.x + bf2f(a1B[j]) * w.y
                  + bf2f(a2B[j]) * w.z + bf2f(a3B[j]) * w.w;
        }

        float* op = out + (size_t)(gbase + li) * Cq;
        __builtin_nontemporal_store(rA, (f32x4*)(op + cA));        // line-complete
        __builtin_nontemporal_store(rB, (f32x4*)(op + cA + 32));   // line-complete
    }
}

// ---------------------------------------------------------------------------
// Fallback (workspace too small): sample directly from (B,C,H,W), fp32 exact.
// ---------------------------------------------------------------------------
__global__ __launch_bounds__(256) void sample_direct_kernel(
    const float* __restrict__ fm,
    const float* __restrict__ verts,
    const float* __restrict__ bary,
    const int*   __restrict__ parents,
    float* __restrict__ out)
{
    const int g = blockIdx.x * 4 + (threadIdx.x >> 6);
    if (g >= TOTAL) return;
    const int lane = threadIdx.x & 63;

    SampleParams sp = compute_center(g, verts, bary, parents);
    const float x0f = floorf(sp.px);
    const float y0f = floorf(sp.py);
    const float fx = sp.px - x0f;
    const float fy = sp.py - y0f;

    const int ix0 = (int)x0f, iy0 = (int)y0f;
    const int ix1 = ix0 + 1,  iy1 = iy0 + 1;

    const float vx0 = (x0f >= 0.0f        && x0f <= (float)(Wq - 1)) ? 1.0f : 0.0f;
    const float vx1 = (x0f + 1.0f >= 0.0f && x0f + 1.0f <= (float)(Wq - 1)) ? 1.0f : 0.0f;
    const float vy0 = (y0f >= 0.0f        && y0f <= (float)(Hq - 1)) ? 1.0f : 0.0f;
    const float vy1 = (y0f + 1.0f >= 0.0f && y0f + 1.0f <= (float)(Hq - 1)) ? 1.0f : 0.0f;

    const int cx0 = min(max(ix0, 0), Wq - 1);
    const int cx1 = min(max(ix1, 0), Wq - 1);
    const int cy0 = min(max(iy0, 0), Hq - 1);
    const int cy1 = min(max(iy1, 0), Hq - 1);

    const float* base = fm + ((size_t)sp.b * Cq + lane) * (Hq * Wq);
    const float v00 = base[cy0 * Wq + cx0] * (vx0 * vy0);
    const float v01 = base[cy0 * Wq + cx1] * (vx1 * vy0);
    const float v10 = base[cy1 * Wq + cx0] * (vx0 * vy1);
    const float v11 = base[cy1 * Wq + cx1] * (vx1 * vy1);

    const float res = (v00 * (1.0f - fx) + v01 * fx) * (1.0f - fy)
                    + (v10 * (1.0f - fx) + v11 * fx) * fy;

    out[(size_t)g * Cq + lane] = res;
}

extern "C" void kernel_launch(void* const* d_in, const int* in_sizes, int n_in,
                              void* d_out, int out_size, void* d_ws, size_t ws_size,
                              hipStream_t stream)
{
    const float* fm      = (const float*)d_in[0];   // (B,C,H,W) fp32
    const float* verts   = (const float*)d_in[1];   // (B,NV,2) fp32
    const float* bary    = (const float*)d_in[2];   // (K,3) fp32
    const int*   parents = (const int*)  d_in[3];   // (N,3) int32
    float* out = (float*)d_out;                     // (B,N,C) fp32

    const int nblk_t = Bq * (Hq * Wq / 64);     // 4096

    if (ws_size >= SZ_FMTB) {
        unsigned short* fmtb = (unsigned short*)d_ws;
        transpose_kernel<<<nblk_t, 256, 0, stream>>>(fm, fmtb);
        sample_kernel<<<NBLK_S, 256, 0, stream>>>(fmtb, verts, bary, parents, out, 0);
        sample_kernel<<<NBLK_S, 256, 0, stream>>>(fmtb, verts, bary, parents, out, 1);
    } else {
        sample_direct_kernel<<<(TOTAL + 3) / 4, 256, 0, stream>>>(fm, verts, bary, parents, out);
    }
}